// Round 4
// baseline (137.810 us; speedup 1.0000x reference)
//
#include <hip/hip_runtime.h>
#include <math.h>

// ================== problem constants ==================
#define BATCH   4096
#define NPUMP   4
#define NCH     100
#define RESPLEN 801

// RK4: 32 steps over 50 km (validated: absmax 1.22e-4 vs threshold 2.11e-4).
#define NSTEPS  32
#define DZ_F    1562.5f
#define HDZ_F   781.25f
#define DZ6_F   260.4166666666667f
#define LOSSC   4.605170185988092e-05f   // 0.0002 * ln(10)/10
#define INV256  0.00390625f              // undo the 2^8 G pre-scale

// ================== structure ==========================
// 16 batch elements per block (= MFMA N). 4 waves (256 thr), no dummy work:
//   w0: row-tiles {0,1}   (rows  0-31)
//   w1: row-tiles {2,3}   (rows 32-63)
//   w2: row-tiles {4,5}   (rows 64-95)  + pump rows 0,1 (100,101)
//   w3: row-tile  {6}     (rows 96-99)  + pump rows 2,3 (102,103)
// Pump rows reuse the wave's B-fragment registers (each lane holds 32 rows
// of its batch column) -> quarter-dots + shfl_xor(16/32) butterfly reduce.
// P staged in LDS as fp16, column-major per batch, double-buffered,
// ONE barrier per RK stage.
#define GB      16
#define ROWSTR  136   // f16 rows per column = 272 B stride (16B-aligned)

typedef _Float16 f16;
typedef _Float16 f16x2 __attribute__((ext_vector_type(2)));
typedef _Float16 f16x8 __attribute__((ext_vector_type(8)));
typedef float    f32x4 __attribute__((ext_vector_type(4)));

union u8x { f16x8 v; f16x2 h[4]; };

#define MFMA16(Aa, Bb, Cc) __builtin_amdgcn_mfma_f32_16x16x32_f16((Aa), (Bb), (Cc), 0, 0, 0)

// Gain entry, scaled by 256 (3.2e12 = 1.25e10 * 2^8) so fp16-quantized
// near-diagonal entries stay normal. Consumers multiply y by INV256.
__device__ __forceinline__ float gentry(float fi, float fj, float invfj,
                                        const float* __restrict__ resp_s)
{
    float D    = fj - fi;
    float ad   = fabsf(D);
    float fidx = ad * 2.0e-11f;          // 1/DF
    int   i0   = (int)fidx;
    i0 = i0 > (RESPLEN - 2) ? (RESPLEN - 2) : i0;
    float w  = fidx - (float)i0;
    float g  = resp_s[i0] * (1.0f - w) + resp_s[i0 + 1] * w;
    g = (D < 0.0f) ? -g : g;
    float ratio = fi * invfj;
    float m  = fmaxf(1.0f, ratio);
    return g * m * 3.2e12f;              // (1/EFFECTIVE_AREA) * 256
}

// One RK stage. Reads P (fp16) from Pls[buf], writes next-stage P to
// Pls[buf^1], one barrier. FIRST_/LAST_ are 0/1 literals.
#define STAGE(A_, W_, FIRST_, LAST_)                                           \
  {                                                                            \
    const f16* pb = (const f16*)&Pls[buf][c][0];                               \
    u8x Bv0, Bv1, Bv2, Bv3;                                                    \
    Bv0.v = *(const f16x8*)(pb + 8 * q);                                       \
    Bv1.v = *(const f16x8*)(pb + 32 + 8 * q);                                  \
    Bv2.v = *(const f16x8*)(pb + 64 + 8 * q);                                  \
    Bv3.v = *(const f16x8*)(pb + 96 + 8 * q);                                  \
    union { uint2 u2; f16x2 h[2]; } ppu;                                       \
    ppu.u2 = *(const uint2*)(pb + 100);                                        \
    f32x4 a01 = {0.f,0.f,0.f,0.f}, a23 = {0.f,0.f,0.f,0.f};                    \
    f32x4 b01 = {0.f,0.f,0.f,0.f}, b23 = {0.f,0.f,0.f,0.f};                    \
    a01 = MFMA16(Af[0][0], Bv0.v, a01);                                        \
    a23 = MFMA16(Af[0][1], Bv1.v, a23);                                        \
    a01 = MFMA16(Af[0][2], Bv2.v, a01);                                        \
    a23 = MFMA16(Af[0][3], Bv3.v, a23);                                        \
    if (wid < 3) {                                                             \
      b01 = MFMA16(Af[1][0], Bv0.v, b01);                                      \
      b23 = MFMA16(Af[1][1], Bv1.v, b23);                                      \
      b01 = MFMA16(Af[1][2], Bv2.v, b01);                                      \
      b23 = MFMA16(Af[1][3], Bv3.v, b23);                                      \
    }                                                                          \
    if (wid >= 2) { /* pump rows PRb,PRb+1 from resident B regs */             \
      float s0 = 0.0f, s1 = 0.0f;                                              \
      _Pragma("unroll")                                                        \
      for (int j = 0; j < 4; ++j) {                                            \
        s0 = __builtin_amdgcn_fdot2(gq[0][0][j], Bv0.h[j], s0, false);         \
        s1 = __builtin_amdgcn_fdot2(gq[1][0][j], Bv0.h[j], s1, false);         \
        s0 = __builtin_amdgcn_fdot2(gq[0][1][j], Bv1.h[j], s0, false);         \
        s1 = __builtin_amdgcn_fdot2(gq[1][1][j], Bv1.h[j], s1, false);         \
        s0 = __builtin_amdgcn_fdot2(gq[0][2][j], Bv2.h[j], s0, false);         \
        s1 = __builtin_amdgcn_fdot2(gq[1][2][j], Bv2.h[j], s1, false);         \
        s0 = __builtin_amdgcn_fdot2(gq[0][3][j], Bv3.h[j], s0, false);         \
        s1 = __builtin_amdgcn_fdot2(gq[1][3][j], Bv3.h[j], s1, false);         \
      }                                                                        \
      s0 += __shfl_xor(s0, 16); s0 += __shfl_xor(s0, 32);                      \
      s1 += __shfl_xor(s1, 16); s1 += __shfl_xor(s1, 32);                      \
      float ssum = (q & 1) ? s1 : s0;                                          \
      float kp = fmaf(ssum, INV256, -LOSSC) * sp;                              \
      if (FIRST_) kps = kp; else kps += (W_) * kp;                             \
      if (LAST_) { P0p += DZ6_F * kps; sp = P0p; }                             \
      else       { sp = fmaf((A_), kp, P0p); }                                 \
      if (q < 2) Pls[buf ^ 1][c][NCH + PRb + q] = (f16)sp;                     \
    }                                                                          \
    { /* tile-0 epilogue (rows row00..row00+3) */                              \
      _Pragma("unroll")                                                        \
      for (int m = 0; m < 4; ++m) {                                            \
        float y = a01[m] + a23[m];                                             \
        y = __builtin_amdgcn_fdot2(gp01[0][m], ppu.h[0], y, false);            \
        y = __builtin_amdgcn_fdot2(gp23[0][m], ppu.h[1], y, false);            \
        float kk = fmaf(y, INV256, -LOSSC) * sv[0][m];                         \
        if (FIRST_) ks[0][m] = kk; else ks[0][m] += (W_) * kk;                 \
        if (LAST_) { P0v[0][m] += DZ6_F * ks[0][m]; sv[0][m] = P0v[0][m]; }    \
        else       { sv[0][m] = fmaf((A_), kk, P0v[0][m]); }                   \
      }                                                                        \
      if (row00 < NCH) {                                                       \
        union { f16x2 h[2]; uint2 u2; } cv;                                    \
        cv.h[0] = f16x2{(f16)sv[0][0], (f16)sv[0][1]};                         \
        cv.h[1] = f16x2{(f16)sv[0][2], (f16)sv[0][3]};                         \
        *(uint2*)&Pls[buf ^ 1][c][row00] = cv.u2;                              \
      }                                                                        \
    }                                                                          \
    if (wid < 3) { /* tile-1 epilogue (rows row01..row01+3, all < 100) */      \
      _Pragma("unroll")                                                        \
      for (int m = 0; m < 4; ++m) {                                            \
        float y = b01[m] + b23[m];                                             \
        y = __builtin_amdgcn_fdot2(gp01[1][m], ppu.h[0], y, false);            \
        y = __builtin_amdgcn_fdot2(gp23[1][m], ppu.h[1], y, false);            \
        float kk = fmaf(y, INV256, -LOSSC) * sv[1][m];                         \
        if (FIRST_) ks[1][m] = kk; else ks[1][m] += (W_) * kk;                 \
        if (LAST_) { P0v[1][m] += DZ6_F * ks[1][m]; sv[1][m] = P0v[1][m]; }    \
        else       { sv[1][m] = fmaf((A_), kk, P0v[1][m]); }                   \
      }                                                                        \
      union { f16x2 h[2]; uint2 u2; } cv;                                      \
      cv.h[0] = f16x2{(f16)sv[1][0], (f16)sv[1][1]};                           \
      cv.h[1] = f16x2{(f16)sv[1][2], (f16)sv[1][3]};                           \
      *(uint2*)&Pls[buf ^ 1][c][row01] = cv.u2;                                \
    }                                                                          \
    __syncthreads();                                                           \
    buf ^= 1;                                                                  \
  }

__global__ __launch_bounds__(256, 1)
void raman_kernel(const float* __restrict__ x,       // (BATCH, 8)
                  const float* __restrict__ resp,    // (801,)
                  const float* __restrict__ sigwl,   // (100,)
                  float* __restrict__ out)           // (BATCH, 100)
{
    // P: rows 0..99 = signal channels, 100..103 = pumps, 104..135 = zero pad
    __shared__ __align__(16) f16 Pls[2][GB][ROWSTR];
    __shared__ float resp_s[RESPLEN + 3];
    __shared__ float sigf[NCH], siginv[NCH];
    __shared__ float pf[GB][NPUMP], pinv[GB][NPUMP], ppw[GB][NPUMP];

    const int tid  = threadIdx.x;
    const int wid  = tid >> 6;
    const int lane = tid & 63;
    const int c    = lane & 15;   // batch column; also A-row-within-tile
    const int q    = lane >> 4;   // quad index (k-group / C-row-group)
    const int b0   = blockIdx.x * GB;
    const int row00 = 32 * wid + 4 * q;        // tile 2*wid
    const int row01 = 32 * wid + 16 + 4 * q;   // tile 2*wid+1 (wid<3 only)
    const int PRb  = (wid == 3) ? 2 : 0;       // pump-row base (wid>=2)

    for (int i = tid; i < RESPLEN; i += 256) resp_s[i] = resp[i];
    for (int i = tid; i < NCH; i += 256) {
        float lam = sigwl[i];
        sigf[i]   = 299792458.0f / lam;
        siginv[i] = lam * 3.3356409519815204e-09f;   // lam/C0
    }
    if (tid < GB * NPUMP) {
        const int cc = tid >> 2, p = tid & 3;
        float lam = x[(b0 + cc) * 8 + p];
        pf[cc][p]   = 299792458.0f / lam;
        pinv[cc][p] = lam * 3.3356409519815204e-09f;
        ppw[cc][p]  = fabsf(x[(b0 + cc) * 8 + NPUMP + p]);
    }
    {   // zero both P buffers (incl. pad rows; pads are never rewritten)
        f16* pz = (f16*)Pls;
        for (int i = tid; i < 2 * GB * ROWSTR; i += 256) pz[i] = (f16)0.0f;
    }
    __syncthreads();

    // ---- A fragments + pump-column couplings for owned tiles ----
    // v_mfma_f32_16x16x32_f16: A[row][k]: row = lane%16, k = 8*(lane/16)+j
    // C/D: col = lane&15 (=batch c), row = 4*(lane>>4) + m
    f16x8 Af[2][4];
    f16x2 gp01[2][4], gp23[2][4];
    #pragma unroll
    for (int t = 0; t < 2; ++t) {
        #pragma unroll
        for (int tc = 0; tc < 4; ++tc)
            Af[t][tc] = f16x8{(f16)0.f,(f16)0.f,(f16)0.f,(f16)0.f,
                              (f16)0.f,(f16)0.f,(f16)0.f,(f16)0.f};
        #pragma unroll
        for (int m = 0; m < 4; ++m) {
            gp01[t][m] = f16x2{(f16)0.f, (f16)0.f};
            gp23[t][m] = f16x2{(f16)0.f, (f16)0.f};
        }
        if (t == 0 || wid < 3) {
            const int tt   = 2 * wid + t;
            const int arow = 16 * tt + c;
            const float fi = (arow < NCH) ? sigf[arow] : 0.0f;
            #pragma unroll
            for (int tc = 0; tc < 4; ++tc) {
                f16x8 a;
                #pragma unroll
                for (int j = 0; j < 8; ++j) {
                    const int k = 32 * tc + 8 * q + j;
                    float v = 0.0f;
                    if (arow < NCH && k < NCH)
                        v = gentry(fi, sigf[k], siginv[k], resp_s);
                    a[j] = (f16)v;
                }
                Af[t][tc] = a;
            }
            #pragma unroll
            for (int m = 0; m < 4; ++m) {
                const int row = 16 * tt + 4 * q + m;
                float v0 = 0.f, v1 = 0.f, v2 = 0.f, v3 = 0.f;
                if (row < NCH) {
                    const float fi2 = sigf[row];
                    v0 = gentry(fi2, pf[c][0], pinv[c][0], resp_s);
                    v1 = gentry(fi2, pf[c][1], pinv[c][1], resp_s);
                    v2 = gentry(fi2, pf[c][2], pinv[c][2], resp_s);
                    v3 = gentry(fi2, pf[c][3], pinv[c][3], resp_s);
                }
                gp01[t][m] = f16x2{(f16)v0, (f16)v1};
                gp23[t][m] = f16x2{(f16)v2, (f16)v3};
            }
        }
    }

    // ---- pump-row gain slices (wid>=2): rows PRb,PRb+1; this lane covers
    // k in {8q..8q+7, 32+8q.., 64+8q.., 96+8q..} (matches B-fragment rows)
    f16x2 gq[2][4][4];
    float P0p = 0.0f, sp = 0.0f, kps = 0.0f;
    if (wid >= 2) {
        #pragma unroll
        for (int r = 0; r < 2; ++r) {
            const float fi = pf[c][PRb + r];
            #pragma unroll
            for (int bc = 0; bc < 4; ++bc) {
                #pragma unroll
                for (int j = 0; j < 4; ++j) {
                    const int k0 = 32 * bc + 8 * q + 2 * j;
                    const int k1 = k0 + 1;
                    float g0 = 0.f, g1 = 0.f;
                    if (k0 < NCH)
                        g0 = gentry(fi, sigf[k0], siginv[k0], resp_s);
                    else if (k0 < NCH + NPUMP)
                        g0 = gentry(fi, pf[c][k0-NCH], pinv[c][k0-NCH], resp_s);
                    if (k1 < NCH)
                        g1 = gentry(fi, sigf[k1], siginv[k1], resp_s);
                    else if (k1 < NCH + NPUMP)
                        g1 = gentry(fi, pf[c][k1-NCH], pinv[c][k1-NCH], resp_s);
                    gq[r][bc][j] = f16x2{(f16)g0, (f16)g1};
                }
            }
        }
        P0p = ppw[c][PRb + (q & 1)];   // q>=2 lanes mirror q&1 (never written)
        sp  = P0p;
    }

    // ---- state init (f32, C-layout) + initial P into buffer 0 ----
    float P0v[2][4], sv[2][4], ks[2][4];
    #pragma unroll
    for (int t = 0; t < 2; ++t)
        #pragma unroll
        for (int m = 0; m < 4; ++m) {
            const int row = 32 * wid + 16 * t + 4 * q + m;
            const bool live = (t == 0 || wid < 3) && row < NCH;
            P0v[t][m] = live ? 1.0e-3f : 0.0f;
            sv[t][m]  = P0v[t][m];
            ks[t][m]  = 0.0f;
        }

    int buf = 0;
    if (row00 < NCH) {
        union { f16x2 h[2]; uint2 u2; } cv;
        cv.h[0] = f16x2{(f16)sv[0][0], (f16)sv[0][1]};
        cv.h[1] = f16x2{(f16)sv[0][2], (f16)sv[0][3]};
        *(uint2*)&Pls[0][c][row00] = cv.u2;
    }
    if (wid < 3) {
        union { f16x2 h[2]; uint2 u2; } cv;
        cv.h[0] = f16x2{(f16)sv[1][0], (f16)sv[1][1]};
        cv.h[1] = f16x2{(f16)sv[1][2], (f16)sv[1][3]};
        *(uint2*)&Pls[0][c][row01] = cv.u2;
    }
    if (wid >= 2 && q < 2) Pls[0][c][NCH + PRb + q] = (f16)sp;
    __syncthreads();

    // ---- RK4 main loop: 32 steps x 4 stages, 1 barrier per stage ----
    #pragma unroll 1
    for (int step = 0; step < NSTEPS; ++step) {
        STAGE(HDZ_F, 1.0f, 1, 0)   // k1
        STAGE(HDZ_F, 2.0f, 0, 0)   // k2
        STAGE(DZ_F,  2.0f, 0, 0)   // k3
        STAGE(0.0f,  1.0f, 0, 1)   // k4 + P0 += dz/6 * ksum
    }

    // ---- output: signal rows 0..99 (float4, 16B-aligned: 400 = 25*16) ----
    if (row00 < NCH) {
        float4 o = make_float4(P0v[0][0], P0v[0][1], P0v[0][2], P0v[0][3]);
        *(float4*)&out[(b0 + c) * NCH + row00] = o;
    }
    if (wid < 3) {
        float4 o = make_float4(P0v[1][0], P0v[1][1], P0v[1][2], P0v[1][3]);
        *(float4*)&out[(b0 + c) * NCH + row01] = o;
    }
}

extern "C" void kernel_launch(void* const* d_in, const int* in_sizes, int n_in,
                              void* d_out, int out_size, void* d_ws, size_t ws_size,
                              hipStream_t stream)
{
    const float* x     = (const float*)d_in[0];
    const float* resp  = (const float*)d_in[1];
    const float* sigwl = (const float*)d_in[2];
    float* out = (float*)d_out;
    raman_kernel<<<BATCH / GB, 256, 0, stream>>>(x, resp, sigwl, out);
}

// Round 5
// 130.764 us; speedup vs baseline: 1.0539x; 1.0539x over previous
//
#include <hip/hip_runtime.h>
#include <math.h>

// ================== problem constants ==================
#define BATCH   4096
#define NPUMP   4
#define NCH     100
#define RESPLEN 801

// RK4: 32 steps over 50 km (validated: absmax 1.22e-4 vs threshold 2.11e-4).
#define NSTEPS  32
#define DZ_F    1562.5f
#define HDZ_F   781.25f
#define DZ6_F   260.4166666666667f
#define LOSSC   4.605170185988092e-05f   // 0.0002 * ln(10)/10
#define INV256  0.00390625f              // undo the 2^8 G pre-scale

// ================== structure ==========================
// GB=8 batch elements per block -> 512 blocks = 2 independent blocks/CU
// (the R4 lesson: 256 blocks = 1 block/CU left every phase serialized).
// 8 waves (512 thr): waves 0..6 one 16-row signal tile each via
// mfma_f32_16x16x32_f16; wave 7 the 4 pump rows via v_dot2.
// MFMA B-columns hold the 8 batches DUPLICATED (lane c and c+8 read the
// same LDS address -> broadcast, free); C/D lanes c>=8 are duplicates and
// their LDS/global writes are gated off.
// P staged in LDS fp16, column-major per batch, double-buffered,
// ONE barrier per RK stage.
#define GB      8
#define ROWSTR  136   // f16 rows per column = 272 B stride (16B-aligned)

typedef _Float16 f16;
typedef _Float16 f16x2 __attribute__((ext_vector_type(2)));
typedef _Float16 f16x8 __attribute__((ext_vector_type(8)));
typedef float    f32x4 __attribute__((ext_vector_type(4)));

#define MFMA16(Aa, Bb, Cc) __builtin_amdgcn_mfma_f32_16x16x32_f16((Aa), (Bb), (Cc), 0, 0, 0)

// Gain entry, scaled by 256 (3.2e12 = 1.25e10 * 2^8) so fp16-quantized
// near-diagonal entries stay normal. Consumers multiply y by INV256.
__device__ __forceinline__ float gentry(float fi, float fj, float invfj,
                                        const float* __restrict__ resp_s)
{
    float D    = fj - fi;
    float ad   = fabsf(D);
    float fidx = ad * 2.0e-11f;          // 1/DF
    int   i0   = (int)fidx;
    i0 = i0 > (RESPLEN - 2) ? (RESPLEN - 2) : i0;
    float w  = fidx - (float)i0;
    float g  = resp_s[i0] * (1.0f - w) + resp_s[i0 + 1] * w;
    g = (D < 0.0f) ? -g : g;
    float ratio = fi * invfj;
    float m  = fmaxf(1.0f, ratio);
    return g * m * 3.2e12f;              // (1/EFFECTIVE_AREA) * 256
}

// One RK stage. Reads P (fp16) from Pls[buf], writes next-stage P to
// Pls[buf^1], one barrier. FIRST_/LAST_ are 0/1 literals.
#define STAGE(A_, W_, FIRST_, LAST_)                                           \
  {                                                                            \
    const f16* pb = (const f16*)&Pls[buf][cb][0];                              \
    if (wid == 7) {                                                            \
      float yp0 = 0.0f, yp1 = 0.0f, yp2 = 0.0f, yp3 = 0.0f;                    \
      _Pragma("unroll")                                                        \
      for (int mb = 0; mb < 13; ++mb) {                                        \
        union { f16x8 v; f16x2 h[4]; } u;                                      \
        u.v = *(const f16x8*)(pb + 8 * mb);                                    \
        yp0 = __builtin_amdgcn_fdot2(gpr[4 * mb + 0], u.h[0], yp0, false);     \
        yp1 = __builtin_amdgcn_fdot2(gpr[4 * mb + 1], u.h[1], yp1, false);     \
        yp2 = __builtin_amdgcn_fdot2(gpr[4 * mb + 2], u.h[2], yp2, false);     \
        yp3 = __builtin_amdgcn_fdot2(gpr[4 * mb + 3], u.h[3], yp3, false);     \
      }                                                                        \
      float ypt = (yp0 + yp1) + (yp2 + yp3);                                   \
      float kp  = fmaf(ypt, INV256, -LOSSC) * sp;                              \
      if (FIRST_) kps = kp; else kps += (W_) * kp;                             \
      if (LAST_) { P0p += DZ6_F * kps; sp = P0p; }                             \
      else       { sp = fmaf((A_), kp, P0p); }                                 \
      if (c < GB) Pls[buf ^ 1][cb][NCH + q] = (f16)sp;                         \
    } else {                                                                   \
      const f16x8 B0 = *(const f16x8*)(pb + 8 * q);                            \
      const f16x8 B1 = *(const f16x8*)(pb + 32 + 8 * q);                       \
      const f16x8 B2 = *(const f16x8*)(pb + 64 + 8 * q);                       \
      const f16x8 B3 = *(const f16x8*)(pb + 96 + 8 * q);                       \
      union { uint2 u2; f16x2 h[2]; } ppu;                                     \
      ppu.u2 = *(const uint2*)(pb + 100);                                      \
      f32x4 a01 = {0.0f, 0.0f, 0.0f, 0.0f};                                    \
      f32x4 a23 = {0.0f, 0.0f, 0.0f, 0.0f};                                    \
      a01 = MFMA16(Af0, B0, a01);                                              \
      a23 = MFMA16(Af1, B1, a23);                                              \
      a01 = MFMA16(Af2, B2, a01);                                              \
      a23 = MFMA16(Af3, B3, a23);                                              \
      _Pragma("unroll")                                                        \
      for (int m = 0; m < 4; ++m) {                                            \
        float y = a01[m] + a23[m];                                             \
        y = __builtin_amdgcn_fdot2(gp01[m], ppu.h[0], y, false);               \
        y = __builtin_amdgcn_fdot2(gp23[m], ppu.h[1], y, false);               \
        float kk = fmaf(y, INV256, -LOSSC) * sv[m];                            \
        if (FIRST_) ks[m] = kk; else ks[m] += (W_) * kk;                       \
        if (LAST_) { P0v[m] += DZ6_F * ks[m]; sv[m] = P0v[m]; }                \
        else       { sv[m] = fmaf((A_), kk, P0v[m]); }                         \
      }                                                                        \
      if (c < GB && row0 < NCH) {                                              \
        union { f16x2 h[2]; uint2 u2; } cv;                                    \
        cv.h[0] = f16x2{(f16)sv[0], (f16)sv[1]};                               \
        cv.h[1] = f16x2{(f16)sv[2], (f16)sv[3]};                               \
        *(uint2*)&Pls[buf ^ 1][cb][row0] = cv.u2;                              \
      }                                                                        \
    }                                                                          \
    __syncthreads();                                                           \
    buf ^= 1;                                                                  \
  }

__global__ __launch_bounds__(512, 1)
void raman_kernel(const float* __restrict__ x,       // (BATCH, 8)
                  const float* __restrict__ resp,    // (801,)
                  const float* __restrict__ sigwl,   // (100,)
                  float* __restrict__ out)           // (BATCH, 100)
{
    // P: rows 0..99 = signal channels, 100..103 = pumps, 104..135 = zero pad
    __shared__ __align__(16) f16 Pls[2][GB][ROWSTR];
    __shared__ float resp_s[RESPLEN + 3];
    __shared__ float sigf[NCH], siginv[NCH];
    __shared__ float pf[GB][NPUMP], pinv[GB][NPUMP], ppw[GB][NPUMP];

    const int tid  = threadIdx.x;
    const int wid  = tid >> 6;
    const int lane = tid & 63;
    const int c    = lane & 15;   // MFMA column; batch = c & 7 (duplicated)
    const int cb   = c & (GB - 1);
    const int q    = lane >> 4;   // quad index (k-group / C-row-group)
    const int b0   = blockIdx.x * GB;
    const int row0 = 16 * wid + 4 * q;   // tile-wave C rows row0..row0+3

    for (int i = tid; i < RESPLEN; i += 512) resp_s[i] = resp[i];
    for (int i = tid; i < NCH; i += 512) {
        float lam = sigwl[i];
        sigf[i]   = 299792458.0f / lam;
        siginv[i] = lam * 3.3356409519815204e-09f;   // lam/C0
    }
    if (tid < GB * NPUMP) {
        const int cc = tid >> 2, p = tid & 3;
        float lam = x[(b0 + cc) * 8 + p];
        pf[cc][p]   = 299792458.0f / lam;
        pinv[cc][p] = lam * 3.3356409519815204e-09f;
        ppw[cc][p]  = fabsf(x[(b0 + cc) * 8 + NPUMP + p]);
    }
    {   // zero both P buffers (incl. pad rows; pads are never rewritten)
        f16* pz = (f16*)Pls;
        for (int i = tid; i < 2 * GB * ROWSTR; i += 512) pz[i] = (f16)0.0f;
    }
    __syncthreads();

    // ---- A fragments: shared signal-signal gain block (fp16, x256) ----
    // v_mfma_f32_16x16x32_f16: A[row][k]: row = lane%16, k = 8*(lane/16)+j
    f16x8 Af0, Af1, Af2, Af3;
    f16x2 gp01[4], gp23[4];
    if (wid < 7) {
        const int arow = 16 * wid + c;
        const float fi = (arow < NCH) ? sigf[arow] : 0.0f;
        f16x8 af[4];
        #pragma unroll
        for (int t = 0; t < 4; ++t) {
            f16x8 a;
            #pragma unroll
            for (int j = 0; j < 8; ++j) {
                const int k = 32 * t + 8 * q + j;
                float v = 0.0f;
                // pump columns (k>=100) excluded: added via gp01/gp23 dot2s
                if (arow < NCH && k < NCH)
                    v = gentry(fi, sigf[k], siginv[k], resp_s);
                a[j] = (f16)v;
            }
            af[t] = a;
        }
        Af0 = af[0]; Af1 = af[1]; Af2 = af[2]; Af3 = af[3];

        // G_sp: batch-specific pump columns for owned C elements
        // C/D: col = lane&15, batch = col&7, row = row0 + m
        #pragma unroll
        for (int m = 0; m < 4; ++m) {
            const int row = row0 + m;
            float v0 = 0.0f, v1 = 0.0f, v2 = 0.0f, v3 = 0.0f;
            if (row < NCH) {
                const float fi2 = sigf[row];
                v0 = gentry(fi2, pf[cb][0], pinv[cb][0], resp_s);
                v1 = gentry(fi2, pf[cb][1], pinv[cb][1], resp_s);
                v2 = gentry(fi2, pf[cb][2], pinv[cb][2], resp_s);
                v3 = gentry(fi2, pf[cb][3], pinv[cb][3], resp_s);
            }
            gp01[m] = f16x2{(f16)v0, (f16)v1};
            gp23[m] = f16x2{(f16)v2, (f16)v3};
        }
    }

    // ---- pump-row gain vectors (wave 7: lane (c,q) -> pump row q, batch cb)
    f16x2 gpr[52];
    float P0p = 0.0f, sp = 0.0f, kps = 0.0f;
    if (wid == 7) {
        const float fi = pf[cb][q];
        #pragma unroll
        for (int d = 0; d < 52; ++d) {
            const int j0 = 2 * d, j1 = 2 * d + 1;
            float f0 = (j0 < NCH) ? sigf[j0]   : pf[cb][j0 - NCH];
            float w0 = (j0 < NCH) ? siginv[j0] : pinv[cb][j0 - NCH];
            float f1 = (j1 < NCH) ? sigf[j1]   : pf[cb][j1 - NCH];
            float w1 = (j1 < NCH) ? siginv[j1] : pinv[cb][j1 - NCH];
            gpr[d] = f16x2{(f16)gentry(fi, f0, w0, resp_s),
                           (f16)gentry(fi, f1, w1, resp_s)};
        }
        P0p = ppw[cb][q];
        sp  = P0p;
    }

    // ---- state init (f32, C-layout) + initial P into buffer 0 ----
    float P0v[4], sv[4], ks[4];
    #pragma unroll
    for (int m = 0; m < 4; ++m) {
        const int row = row0 + m;
        P0v[m] = (wid < 7 && row < NCH) ? 1.0e-3f : 0.0f;
        sv[m]  = P0v[m];
        ks[m]  = 0.0f;
    }

    int buf = 0;
    if (wid < 7 && c < GB && row0 < NCH) {
        union { f16x2 h[2]; uint2 u2; } cv;
        cv.h[0] = f16x2{(f16)sv[0], (f16)sv[1]};
        cv.h[1] = f16x2{(f16)sv[2], (f16)sv[3]};
        *(uint2*)&Pls[0][cb][row0] = cv.u2;
    }
    if (wid == 7 && c < GB) Pls[0][cb][NCH + q] = (f16)sp;
    __syncthreads();

    // ---- RK4 main loop: 32 steps x 4 stages, 1 barrier per stage ----
    #pragma unroll 1
    for (int step = 0; step < NSTEPS; ++step) {
        STAGE(HDZ_F, 1.0f, 1, 0)   // k1
        STAGE(HDZ_F, 2.0f, 0, 0)   // k2
        STAGE(DZ_F,  2.0f, 0, 0)   // k3
        STAGE(0.0f,  1.0f, 0, 1)   // k4 + P0 += dz/6 * ksum
    }

    // ---- output: signal rows 0..99 (float4, 16B-aligned: 400 = 25*16) ----
    if (wid < 7 && c < GB && row0 < NCH) {
        float4 o = make_float4(P0v[0], P0v[1], P0v[2], P0v[3]);
        *(float4*)&out[(b0 + cb) * NCH + row0] = o;
    }
}

extern "C" void kernel_launch(void* const* d_in, const int* in_sizes, int n_in,
                              void* d_out, int out_size, void* d_ws, size_t ws_size,
                              hipStream_t stream)
{
    const float* x     = (const float*)d_in[0];
    const float* resp  = (const float*)d_in[1];
    const float* sigwl = (const float*)d_in[2];
    float* out = (float*)d_out;
    raman_kernel<<<BATCH / GB, 512, 0, stream>>>(x, resp, sigwl, out);
}